// Round 1
// baseline (283.496 us; speedup 1.0000x reference)
//
#include <hip/hip_runtime.h>

// MHA forward: B=4, S=2048, D=768, H=12, Hd=64
// Pipeline: cvt(x,w) -> qkv GEMM (fp16 MFMA) -> flash attn -> proj GEMM.
// All MFMA accumulate in fp32; fp16 chosen over bf16 for the ~2.1e-3 absmax budget.

typedef _Float16 f16;
typedef _Float16 f16x8 __attribute__((ext_vector_type(8)));
typedef _Float16 f16x4 __attribute__((ext_vector_type(4)));
typedef float f32x4 __attribute__((ext_vector_type(4)));

#define BQ 4
#define SQ 2048
#define DQ 768
#define HQ 12
#define HD 64
#define M_TOK (BQ*SQ)      // 8192

__device__ __forceinline__ void gld_lds16(const f16* g, f16* l) {
  __builtin_amdgcn_global_load_lds((const __attribute__((address_space(1))) void*)g,
                                   (__attribute__((address_space(3))) void*)l,
                                   16, 0, 0);
}

// ---- converts ----
__global__ void cvt_x(const float* __restrict__ x, f16* __restrict__ xh, int n) {
  int i = (blockIdx.x * blockDim.x + threadIdx.x) * 4;
  if (i < n) {
    float4 v = *(const float4*)(x + i);
    f16x4 o = { (f16)v.x, (f16)v.y, (f16)v.z, (f16)v.w };
    *(f16x4*)(xh + i) = o;
  }
}

// w [K][N] f32 -> wt [N][K] f16, 32x32 LDS tiles
__global__ void cvt_transpose(const float* __restrict__ w, f16* __restrict__ wt, int K, int N) {
  __shared__ float tile[32][33];
  int nb = blockIdx.x * 32, kb = blockIdx.y * 32;
  int tx = threadIdx.x & 31, ty = threadIdx.x >> 5;   // 256 thr: ty 0..7
  for (int r = ty; r < 32; r += 8)
    tile[r][tx] = w[(size_t)(kb + r) * N + nb + tx];
  __syncthreads();
  for (int r = ty; r < 32; r += 8)
    wt[(size_t)(nb + r) * K + kb + tx] = (f16)tile[tx][r];
}

// ---- 128x128 tile GEMM, A [M][K] f16, Bt [N][K] f16 (pre-transposed), BK=32 ----
// MODE 0: qkv epilogue (bias + scatter Q*0.125, K, V^T)
// MODE 1: proj epilogue (bias + f32 out)
template<int MODE>
__global__ __launch_bounds__(256, 2)
void gemm128(const f16* __restrict__ A, const f16* __restrict__ Bt,
             const float* __restrict__ bias, float* __restrict__ Cf,
             f16* __restrict__ Qb, f16* __restrict__ Kb, f16* __restrict__ Vt,
             int M, int N, int K, int nbx)
{
  __shared__ f16 Ash[128 * 32];
  __shared__ f16 Bsh[128 * 32];
  const int tid = threadIdx.x;
  const int bid = blockIdx.x;
  const int nb = bid % nbx, mb = bid / nbx;
  const int m0 = mb * 128, n0 = nb * 128;
  const int lane = tid & 63, wid = tid >> 6;
  const int wr = wid >> 1, wc = wid & 1;
  const int l16 = lane & 15, l4 = lane >> 4;

  f32x4 acc[4][4] = {};

  // linear staging: chunk f -> LDS bytes [f*16, f*16+16), global row f/4, col-bytes (f&3)*16
  const int f0 = tid, f1 = tid + 256;
  const f16* a0 = A + (size_t)(m0 + (f0 >> 2)) * K + (f0 & 3) * 8;
  const f16* a1 = A + (size_t)(m0 + (f1 >> 2)) * K + (f1 & 3) * 8;
  const f16* b0 = Bt + (size_t)(n0 + (f0 >> 2)) * K + (f0 & 3) * 8;
  const f16* b1 = Bt + (size_t)(n0 + (f1 >> 2)) * K + (f1 & 3) * 8;
  f16* lA0 = Ash + f0 * 8; f16* lA1 = Ash + f1 * 8;
  f16* lB0 = Bsh + f0 * 8; f16* lB1 = Bsh + f1 * 8;

  for (int k0 = 0; k0 < K; k0 += 32) {
    gld_lds16(a0 + k0, lA0);
    gld_lds16(a1 + k0, lA1);
    gld_lds16(b0 + k0, lB0);
    gld_lds16(b1 + k0, lB1);
    __syncthreads();
    f16x8 af[4], bfr[4];
    #pragma unroll
    for (int m = 0; m < 4; ++m)
      af[m] = *(const f16x8*)(Ash + (wr * 64 + m * 16 + l16) * 32 + l4 * 8);
    #pragma unroll
    for (int n = 0; n < 4; ++n)
      bfr[n] = *(const f16x8*)(Bsh + (wc * 64 + n * 16 + l16) * 32 + l4 * 8);
    #pragma unroll
    for (int m = 0; m < 4; ++m)
      #pragma unroll
      for (int n = 0; n < 4; ++n)
        acc[m][n] = __builtin_amdgcn_mfma_f32_16x16x32_f16(af[m], bfr[n], acc[m][n], 0, 0, 0);
    __syncthreads();
  }

  const int cbase = n0 + wc * 64;
  const int rbase = m0 + wr * 64;
  if (MODE == 1) {
    #pragma unroll
    for (int n = 0; n < 4; ++n) {
      int c = cbase + n * 16 + l16;
      float bv = bias[c];
      #pragma unroll
      for (int m = 0; m < 4; ++m)
        #pragma unroll
        for (int r = 0; r < 4; ++r) {
          int rr = rbase + m * 16 + l4 * 4 + r;
          Cf[(size_t)rr * N + c] = acc[m][n][r] + bv;
        }
    }
  } else {
    #pragma unroll
    for (int n = 0; n < 4; ++n) {
      int c = cbase + n * 16 + l16;
      float bv = bias[c];
      int which = c / DQ;
      int rem = c - which * DQ;
      int h = rem >> 6, hd = rem & 63;
      #pragma unroll
      for (int m = 0; m < 4; ++m)
        #pragma unroll
        for (int r = 0; r < 4; ++r) {
          int rr = rbase + m * 16 + l4 * 4 + r;
          int b = rr >> 11, s = rr & 2047;
          float v = acc[m][n][r] + bv;
          size_t bh = (size_t)(b * HQ + h);
          if (which == 0)      Qb[(bh * SQ + s) * HD + hd] = (f16)(v * 0.125f); // fold 1/sqrt(64), exact
          else if (which == 1) Kb[(bh * SQ + s) * HD + hd] = (f16)v;
          else                 Vt[(bh * HD + hd) * SQ + s] = (f16)v;            // V transposed
        }
    }
  }
}

// ---- flash attention: 1 block = 128 q rows (4 independent waves x 32 rows), KV tile 64 ----
__global__ __launch_bounds__(256, 2)
void attn(const f16* __restrict__ Qb, const f16* __restrict__ Kb,
          const f16* __restrict__ Vt, f16* __restrict__ O)
{
  __shared__ f16 Pl[4][32 * 72];  // per-wave P buffer, row stride 72 (144B, 16B-aligned, bank-spread)
  const int tid = threadIdx.x, lane = tid & 63, wid = tid >> 6;
  const int l16 = lane & 15, l4 = lane >> 4;
  const int qt = blockIdx.x & 15, bh = blockIdx.x >> 4;
  const int b = bh / HQ, h = bh - b * HQ;
  const f16* q  = Qb + (size_t)bh * SQ * HD;
  const f16* kp = Kb + (size_t)bh * SQ * HD;
  const f16* vp = Vt + (size_t)bh * HD * SQ;
  f16* pl = &Pl[wid][0];
  const int s0 = qt * 128 + wid * 32;

  f16x8 qf[2][2];
  #pragma unroll
  for (int m = 0; m < 2; ++m)
    #pragma unroll
    for (int kk = 0; kk < 2; ++kk)
      qf[m][kk] = *(const f16x8*)(q + (size_t)(s0 + m * 16 + l16) * HD + kk * 32 + l4 * 8);

  f32x4 oacc[2][4] = {};
  float mrun[2][4], lrun[2][4];
  #pragma unroll
  for (int m = 0; m < 2; ++m)
    #pragma unroll
    for (int r = 0; r < 4; ++r) { mrun[m][r] = -1e30f; lrun[m][r] = 0.f; }

  for (int t0 = 0; t0 < SQ; t0 += 64) {
    // S^tile = Q K^T (rows s, cols t)
    f32x4 sacc[2][4] = {};
    #pragma unroll
    for (int kk = 0; kk < 2; ++kk) {
      f16x8 kf[4];
      #pragma unroll
      for (int n = 0; n < 4; ++n)
        kf[n] = *(const f16x8*)(kp + (size_t)(t0 + n * 16 + l16) * HD + kk * 32 + l4 * 8);
      #pragma unroll
      for (int m = 0; m < 2; ++m)
        #pragma unroll
        for (int n = 0; n < 4; ++n)
          sacc[m][n] = __builtin_amdgcn_mfma_f32_16x16x32_f16(qf[m][kk], kf[n], sacc[m][n], 0, 0, 0);
    }
    // online softmax; row = m*16 + l4*4 + r, cols spread over l16 and n
    #pragma unroll
    for (int m = 0; m < 2; ++m) {
      #pragma unroll
      for (int r = 0; r < 4; ++r) {
        float rm = fmaxf(fmaxf(sacc[m][0][r], sacc[m][1][r]), fmaxf(sacc[m][2][r], sacc[m][3][r]));
        rm = fmaxf(rm, __shfl_xor(rm, 1));
        rm = fmaxf(rm, __shfl_xor(rm, 2));
        rm = fmaxf(rm, __shfl_xor(rm, 4));
        rm = fmaxf(rm, __shfl_xor(rm, 8));
        float mo = mrun[m][r];
        float mn = fmaxf(mo, rm);
        float corr = __expf(mo - mn);
        mrun[m][r] = mn;
        float ps = 0.f;
        #pragma unroll
        for (int n = 0; n < 4; ++n) {
          float p = __expf(sacc[m][n][r] - mn);
          sacc[m][n][r] = p;
          ps += p;
        }
        ps += __shfl_xor(ps, 1);
        ps += __shfl_xor(ps, 2);
        ps += __shfl_xor(ps, 4);
        ps += __shfl_xor(ps, 8);
        lrun[m][r] = lrun[m][r] * corr + ps;
        #pragma unroll
        for (int n = 0; n < 4; ++n)
          oacc[m][n][r] *= corr;
      }
    }
    // P -> per-wave LDS (layout fix: C-layout -> A-fragment layout). No barrier: same wave.
    #pragma unroll
    for (int m = 0; m < 2; ++m)
      #pragma unroll
      for (int n = 0; n < 4; ++n)
        #pragma unroll
        for (int r = 0; r < 4; ++r)
          pl[(m * 16 + l4 * 4 + r) * 72 + n * 16 + l16] = (f16)sacc[m][n][r];
    f16x8 pf[2][2];
    #pragma unroll
    for (int m = 0; m < 2; ++m)
      #pragma unroll
      for (int kk = 0; kk < 2; ++kk)
        pf[m][kk] = *(const f16x8*)(pl + (m * 16 + l16) * 72 + kk * 32 + l4 * 8);
    // O += P V  (B-frags direct from V^T global: contiguous 16B)
    #pragma unroll
    for (int kk = 0; kk < 2; ++kk) {
      f16x8 vf[4];
      #pragma unroll
      for (int n = 0; n < 4; ++n)
        vf[n] = *(const f16x8*)(vp + (size_t)(n * 16 + l16) * SQ + t0 + kk * 32 + l4 * 8);
      #pragma unroll
      for (int m = 0; m < 2; ++m)
        #pragma unroll
        for (int n = 0; n < 4; ++n)
          oacc[m][n] = __builtin_amdgcn_mfma_f32_16x16x32_f16(pf[m][kk], vf[n], oacc[m][n], 0, 0, 0);
    }
  }
  // normalize + store to [B,S,D] fp16
  #pragma unroll
  for (int m = 0; m < 2; ++m)
    #pragma unroll
    for (int r = 0; r < 4; ++r) {
      float inv = 1.f / lrun[m][r];
      int s = s0 + m * 16 + l4 * 4 + r;
      size_t base = ((size_t)b * SQ + s) * DQ + h * HD;
      #pragma unroll
      for (int n = 0; n < 4; ++n)
        O[base + n * 16 + l16] = (f16)(oacc[m][n][r] * inv);
    }
}

extern "C" void kernel_launch(void* const* d_in, const int* in_sizes, int n_in,
                              void* d_out, int out_size, void* d_ws, size_t ws_size,
                              hipStream_t stream) {
  const float* x      = (const float*)d_in[0];
  const float* w_qkv  = (const float*)d_in[1];
  const float* b_qkv  = (const float*)d_in[2];
  const float* w_proj = (const float*)d_in[3];
  const float* b_proj = (const float*)d_in[4];
  float* out = (float*)d_out;

  char* ws = (char*)d_ws;
  f16* xh     = (f16*)ws; ws += (size_t)M_TOK * DQ * 2;        // 12.6 MB (reused as attn-out)
  f16* wqkvT  = (f16*)ws; ws += (size_t)3 * DQ * DQ * 2;       // 3.5 MB  [2304][768]
  f16* wprojT = (f16*)ws; ws += (size_t)DQ * DQ * 2;           // 1.2 MB  [768][768]
  f16* Qb     = (f16*)ws; ws += (size_t)M_TOK * DQ * 2;        // 12.6 MB [B,H,S,64]
  f16* Kb     = (f16*)ws; ws += (size_t)M_TOK * DQ * 2;        // 12.6 MB [B,H,S,64]
  f16* Vt     = (f16*)ws; ws += (size_t)M_TOK * DQ * 2;        // 12.6 MB [B,H,64,S]
  f16* AO     = xh;  // attn output [B,S,D]; xh fully consumed by qkv GEMM before attn runs

  cvt_x<<<(M_TOK * DQ) / (256 * 4), 256, 0, stream>>>(x, xh, M_TOK * DQ);
  cvt_transpose<<<dim3((3 * DQ) / 32, DQ / 32), 256, 0, stream>>>(w_qkv, wqkvT, DQ, 3 * DQ);
  cvt_transpose<<<dim3(DQ / 32, DQ / 32), 256, 0, stream>>>(w_proj, wprojT, DQ, DQ);

  gemm128<0><<<(M_TOK / 128) * (3 * DQ / 128), 256, 0, stream>>>(
      xh, wqkvT, b_qkv, nullptr, Qb, Kb, Vt, M_TOK, 3 * DQ, DQ, 3 * DQ / 128);

  attn<<<BQ * HQ * (SQ / 128), 256, 0, stream>>>(Qb, Kb, Vt, AO);

  gemm128<1><<<(M_TOK / 128) * (DQ / 128), 256, 0, stream>>>(
      AO, wprojT, b_proj, out, nullptr, nullptr, nullptr, M_TOK, DQ, DQ, DQ / 128);
}

// Round 2
// 264.538 us; speedup vs baseline: 1.0717x; 1.0717x over previous
//
#include <hip/hip_runtime.h>

// MHA forward: B=4, S=2048, D=768, H=12, Hd=64
// cvt(x,w) -> qkv GEMM (fp16 MFMA) -> flash attn (LDS-shared KV) -> proj GEMM.

typedef _Float16 f16;
typedef _Float16 f16x8 __attribute__((ext_vector_type(8)));
typedef _Float16 f16x4 __attribute__((ext_vector_type(4)));
typedef float f32x4 __attribute__((ext_vector_type(4)));

#define BQ 4
#define SQ 2048
#define DQ 768
#define HQ 12
#define HD 64
#define M_TOK (BQ*SQ)      // 8192
#define KVB 64

__device__ __forceinline__ void gld_lds16(const f16* g, f16* l) {
  __builtin_amdgcn_global_load_lds((const __attribute__((address_space(1))) void*)g,
                                   (__attribute__((address_space(3))) void*)l,
                                   16, 0, 0);
}

// ---- converts ----
__global__ void cvt_x(const float* __restrict__ x, f16* __restrict__ xh, int n) {
  int i = (blockIdx.x * blockDim.x + threadIdx.x) * 4;
  if (i < n) {
    float4 v = *(const float4*)(x + i);
    f16x4 o = { (f16)v.x, (f16)v.y, (f16)v.z, (f16)v.w };
    *(f16x4*)(xh + i) = o;
  }
}

// w [K][N] f32 -> wt [N][K] f16
__global__ void cvt_transpose(const float* __restrict__ w, f16* __restrict__ wt, int K, int N) {
  __shared__ float tile[32][33];
  int nb = blockIdx.x * 32, kb = blockIdx.y * 32;
  int tx = threadIdx.x & 31, ty = threadIdx.x >> 5;
  for (int r = ty; r < 32; r += 8)
    tile[r][tx] = w[(size_t)(kb + r) * N + nb + tx];
  __syncthreads();
  for (int r = ty; r < 32; r += 8)
    wt[(size_t)(nb + r) * K + kb + tx] = (f16)tile[tx][r];
}

// ---- 128x128 tile GEMM, A [M][K] f16, Bt [N][K] f16, BK=32 ----
template<int MODE>
__global__ __launch_bounds__(256, 2)
void gemm128(const f16* __restrict__ A, const f16* __restrict__ Bt,
             const float* __restrict__ bias, float* __restrict__ Cf,
             f16* __restrict__ Qb, f16* __restrict__ Kb, f16* __restrict__ Vt,
             int M, int N, int K, int nbx)
{
  __shared__ f16 Ash[128 * 32];
  __shared__ f16 Bsh[128 * 32];
  const int tid = threadIdx.x;
  const int bid = blockIdx.x;
  const int nb = bid % nbx, mb = bid / nbx;
  const int m0 = mb * 128, n0 = nb * 128;
  const int lane = tid & 63, wid = tid >> 6;
  const int wr = wid >> 1, wc = wid & 1;
  const int l16 = lane & 15, l4 = lane >> 4;

  f32x4 acc[4][4] = {};

  const int f0 = tid, f1 = tid + 256;
  const f16* a0 = A + (size_t)(m0 + (f0 >> 2)) * K + (f0 & 3) * 8;
  const f16* a1 = A + (size_t)(m0 + (f1 >> 2)) * K + (f1 & 3) * 8;
  const f16* b0 = Bt + (size_t)(n0 + (f0 >> 2)) * K + (f0 & 3) * 8;
  const f16* b1 = Bt + (size_t)(n0 + (f1 >> 2)) * K + (f1 & 3) * 8;
  f16* lA0 = Ash + f0 * 8; f16* lA1 = Ash + f1 * 8;
  f16* lB0 = Bsh + f0 * 8; f16* lB1 = Bsh + f1 * 8;

  for (int k0 = 0; k0 < K; k0 += 32) {
    gld_lds16(a0 + k0, lA0);
    gld_lds16(a1 + k0, lA1);
    gld_lds16(b0 + k0, lB0);
    gld_lds16(b1 + k0, lB1);
    __syncthreads();
    f16x8 af[4], bfr[4];
    #pragma unroll
    for (int m = 0; m < 4; ++m)
      af[m] = *(const f16x8*)(Ash + (wr * 64 + m * 16 + l16) * 32 + l4 * 8);
    #pragma unroll
    for (int n = 0; n < 4; ++n)
      bfr[n] = *(const f16x8*)(Bsh + (wc * 64 + n * 16 + l16) * 32 + l4 * 8);
    #pragma unroll
    for (int m = 0; m < 4; ++m)
      #pragma unroll
      for (int n = 0; n < 4; ++n)
        acc[m][n] = __builtin_amdgcn_mfma_f32_16x16x32_f16(af[m], bfr[n], acc[m][n], 0, 0, 0);
    __syncthreads();
  }

  const int cbase = n0 + wc * 64;
  const int rbase = m0 + wr * 64;
  if (MODE == 1) {
    #pragma unroll
    for (int n = 0; n < 4; ++n) {
      int c = cbase + n * 16 + l16;
      float bv = bias[c];
      #pragma unroll
      for (int m = 0; m < 4; ++m)
        #pragma unroll
        for (int r = 0; r < 4; ++r) {
          int rr = rbase + m * 16 + l4 * 4 + r;
          Cf[(size_t)rr * N + c] = acc[m][n][r] + bv;
        }
    }
  } else {
    #pragma unroll
    for (int n = 0; n < 4; ++n) {
      int c = cbase + n * 16 + l16;
      float bv = bias[c];
      int which = c / DQ;
      int rem = c - which * DQ;
      int h = rem >> 6, hd = rem & 63;
      #pragma unroll
      for (int m = 0; m < 4; ++m)
        #pragma unroll
        for (int r = 0; r < 4; ++r) {
          int rr = rbase + m * 16 + l4 * 4 + r;
          int b = rr >> 11, s = rr & 2047;
          float v = acc[m][n][r] + bv;
          size_t bh = (size_t)(b * HQ + h);
          if (which == 0)      Qb[(bh * SQ + s) * HD + hd] = (f16)(v * 0.125f);
          else if (which == 1) Kb[(bh * SQ + s) * HD + hd] = (f16)v;
          else                 Vt[(bh * HD + hd) * SQ + s] = (f16)v;
        }
    }
  }
}

// ---- flash attention v2 ----
// 1 block = 64 q rows (4 waves x 16), KV tile 64 shared via LDS (single buffer).
// K/V LDS tiles XOR-swizzled (byte ^= (row&7)<<4) via pre-swizzled global source.
__global__ __launch_bounds__(256, 6)
void attn(const f16* __restrict__ Qb, const f16* __restrict__ Kb,
          const f16* __restrict__ Vt, f16* __restrict__ O)
{
  __shared__ f16 Ksh[KVB * HD];      // [t'][d] swizzled, 8 KB
  __shared__ f16 Vsh[HD * KVB];      // [d][t'] swizzled, 8 KB
  __shared__ f16 Pl[4][16 * 72];     // per-wave P, 9 KB
  const int tid = threadIdx.x, lane = tid & 63, wid = tid >> 6;
  const int l16 = lane & 15, l4 = lane >> 4;

  // bijective XCD swizzle: 1536 blocks, 192/XCD -> 6 whole heads per XCD L2
  const int nwg = gridDim.x;
  const int cpx = nwg >> 3;
  const int swz = (blockIdx.x & 7) * cpx + (blockIdx.x >> 3);
  const int qt = swz & 31, bh = swz >> 5;
  const int b = bh / HQ, h = bh - b * HQ;
  const f16* q  = Qb + (size_t)bh * SQ * HD;
  const f16* kp = Kb + (size_t)bh * SQ * HD;
  const f16* vp = Vt + (size_t)bh * HD * SQ;
  f16* pl = &Pl[wid][0];
  const int s0 = qt * 64 + wid * 16;

  // Q fragments (A-frag): row = l16, k = kk*32 + l4*8
  f16x8 qf[2];
  #pragma unroll
  for (int kk = 0; kk < 2; ++kk)
    qf[kk] = *(const f16x8*)(q + (size_t)(s0 + l16) * HD + kk * 32 + l4 * 8);

  f32x4 oacc[4] = {};
  float mrun[4], lrun[4];
  #pragma unroll
  for (int r = 0; r < 4; ++r) { mrun[r] = -1e30f; lrun[r] = 0.f; }

  // staging geometry: thread covers LDS bytes [tid*16, tid*16+16); row = tid/8,
  // source col-chunk pre-swizzled so LDS-linear == swizzled layout
  const int srow = tid >> 3;
  const int scol = ((tid & 7) ^ (srow & 7)) * 8;   // f16 units

  for (int t0 = 0; t0 < SQ; t0 += KVB) {
    __syncthreads();  // everyone done reading previous tile
    gld_lds16(kp + (size_t)(t0 + srow) * HD + scol,      Ksh + tid * 8);
    gld_lds16(kp + (size_t)(t0 + srow + 32) * HD + scol, Ksh + (tid + 256) * 8);
    gld_lds16(vp + (size_t)srow * SQ + t0 + scol,        Vsh + tid * 8);
    gld_lds16(vp + (size_t)(srow + 32) * SQ + t0 + scol, Vsh + (tid + 256) * 8);
    __syncthreads();  // drains vmcnt: tiles ready

    // S = Q K^T
    f32x4 sacc[4] = {};
    #pragma unroll
    for (int kk = 0; kk < 2; ++kk) {
      f16x8 kf[4];
      #pragma unroll
      for (int n = 0; n < 4; ++n) {
        int row = n * 16 + l16;
        int col = (kk * 32 + l4 * 8) ^ ((l16 & 7) * 8);
        kf[n] = *(const f16x8*)(Ksh + row * HD + col);
      }
      #pragma unroll
      for (int n = 0; n < 4; ++n)
        sacc[n] = __builtin_amdgcn_mfma_f32_16x16x32_f16(qf[kk], kf[n], sacc[n], 0, 0, 0);
    }

    // online softmax; row = l4*4 + r, cols over l16 and n
    #pragma unroll
    for (int r = 0; r < 4; ++r) {
      float rm = fmaxf(fmaxf(sacc[0][r], sacc[1][r]), fmaxf(sacc[2][r], sacc[3][r]));
      rm = fmaxf(rm, __shfl_xor(rm, 1));
      rm = fmaxf(rm, __shfl_xor(rm, 2));
      rm = fmaxf(rm, __shfl_xor(rm, 4));
      rm = fmaxf(rm, __shfl_xor(rm, 8));
      float mo = mrun[r];
      float mn = fmaxf(mo, rm);
      float corr = __expf(mo - mn);
      mrun[r] = mn;
      float ps = 0.f;
      #pragma unroll
      for (int n = 0; n < 4; ++n) {
        float p = __expf(sacc[n][r] - mn);
        sacc[n][r] = p;
        ps += p;
      }
      ps += __shfl_xor(ps, 1);
      ps += __shfl_xor(ps, 2);
      ps += __shfl_xor(ps, 4);
      ps += __shfl_xor(ps, 8);
      lrun[r] = lrun[r] * corr + ps;
      #pragma unroll
      for (int n = 0; n < 4; ++n)
        oacc[n][r] *= corr;
    }

    // P -> per-wave LDS (C-layout -> A-frag layout), no barrier: same wave
    #pragma unroll
    for (int n = 0; n < 4; ++n)
      #pragma unroll
      for (int r = 0; r < 4; ++r)
        pl[(l4 * 4 + r) * 72 + n * 16 + l16] = (f16)sacc[n][r];
    f16x8 pf[2];
    #pragma unroll
    for (int kk = 0; kk < 2; ++kk)
      pf[kk] = *(const f16x8*)(pl + l16 * 72 + kk * 32 + l4 * 8);

    // O += P V  (B-frag from swizzled Vsh)
    #pragma unroll
    for (int kk = 0; kk < 2; ++kk) {
      f16x8 vf[4];
      #pragma unroll
      for (int n = 0; n < 4; ++n) {
        int row = n * 16 + l16;
        int col = (kk * 32 + l4 * 8) ^ ((l16 & 7) * 8);
        vf[n] = *(const f16x8*)(Vsh + row * KVB + col);
      }
      #pragma unroll
      for (int n = 0; n < 4; ++n)
        oacc[n] = __builtin_amdgcn_mfma_f32_16x16x32_f16(pf[kk], vf[n], oacc[n], 0, 0, 0);
    }
  }

  // normalize + store [B,S,D] fp16
  #pragma unroll
  for (int r = 0; r < 4; ++r) {
    float inv = 1.f / lrun[r];
    int s = s0 + l4 * 4 + r;
    size_t base = ((size_t)b * SQ + s) * DQ + h * HD;
    #pragma unroll
    for (int n = 0; n < 4; ++n)
      O[base + n * 16 + l16] = (f16)(oacc[n][r] * inv);
  }
}

extern "C" void kernel_launch(void* const* d_in, const int* in_sizes, int n_in,
                              void* d_out, int out_size, void* d_ws, size_t ws_size,
                              hipStream_t stream) {
  const float* x      = (const float*)d_in[0];
  const float* w_qkv  = (const float*)d_in[1];
  const float* b_qkv  = (const float*)d_in[2];
  const float* w_proj = (const float*)d_in[3];
  const float* b_proj = (const float*)d_in[4];
  float* out = (float*)d_out;

  char* ws = (char*)d_ws;
  f16* xh     = (f16*)ws; ws += (size_t)M_TOK * DQ * 2;
  f16* wqkvT  = (f16*)ws; ws += (size_t)3 * DQ * DQ * 2;
  f16* wprojT = (f16*)ws; ws += (size_t)DQ * DQ * 2;
  f16* Qb     = (f16*)ws; ws += (size_t)M_TOK * DQ * 2;
  f16* Kb     = (f16*)ws; ws += (size_t)M_TOK * DQ * 2;
  f16* Vt     = (f16*)ws; ws += (size_t)M_TOK * DQ * 2;
  f16* AO     = xh;  // attn output; xh fully consumed by qkv GEMM before attn

  cvt_x<<<(M_TOK * DQ) / (256 * 4), 256, 0, stream>>>(x, xh, M_TOK * DQ);
  cvt_transpose<<<dim3((3 * DQ) / 32, DQ / 32), 256, 0, stream>>>(w_qkv, wqkvT, DQ, 3 * DQ);
  cvt_transpose<<<dim3(DQ / 32, DQ / 32), 256, 0, stream>>>(w_proj, wprojT, DQ, DQ);

  gemm128<0><<<(M_TOK / 128) * (3 * DQ / 128), 256, 0, stream>>>(
      xh, wqkvT, b_qkv, nullptr, Qb, Kb, Vt, M_TOK, 3 * DQ, DQ, 3 * DQ / 128);

  attn<<<BQ * HQ * (SQ / 64), 256, 0, stream>>>(Qb, Kb, Vt, AO);

  gemm128<1><<<(M_TOK / 128) * (DQ / 128), 256, 0, stream>>>(
      AO, wprojT, b_proj, out, nullptr, nullptr, nullptr, M_TOK, DQ, DQ, DQ / 128);
}

// Round 3
// 195.428 us; speedup vs baseline: 1.4506x; 1.3536x over previous
//
#include <hip/hip_runtime.h>

// MHA forward: B=4, S=2048, D=768, H=12, Hd=64
// cvt(x,w) -> qkv GEMM (fp16 MFMA) -> flash attn (swapped-QK, in-reg softmax,
// permuted-K staging, double-buffered LDS) -> proj GEMM.

typedef _Float16 f16;
typedef _Float16 f16x8 __attribute__((ext_vector_type(8)));
typedef _Float16 f16x4 __attribute__((ext_vector_type(4)));
typedef float f32x4 __attribute__((ext_vector_type(4)));

#define BQ 4
#define SQ 2048
#define DQ 768
#define HQ 12
#define HD 64
#define M_TOK (BQ*SQ)      // 8192
#define KVB 64

__device__ __forceinline__ void gld_lds16(const f16* g, f16* l) {
  __builtin_amdgcn_global_load_lds((const __attribute__((address_space(1))) void*)g,
                                   (__attribute__((address_space(3))) void*)l,
                                   16, 0, 0);
}

// ---- converts ----
__global__ void cvt_x(const float* __restrict__ x, f16* __restrict__ xh, int n) {
  int i = (blockIdx.x * blockDim.x + threadIdx.x) * 4;
  if (i < n) {
    float4 v = *(const float4*)(x + i);
    f16x4 o = { (f16)v.x, (f16)v.y, (f16)v.z, (f16)v.w };
    *(f16x4*)(xh + i) = o;
  }
}

// w [K][N] f32 -> wt [N][K] f16
__global__ void cvt_transpose(const float* __restrict__ w, f16* __restrict__ wt, int K, int N) {
  __shared__ float tile[32][33];
  int nb = blockIdx.x * 32, kb = blockIdx.y * 32;
  int tx = threadIdx.x & 31, ty = threadIdx.x >> 5;
  for (int r = ty; r < 32; r += 8)
    tile[r][tx] = w[(size_t)(kb + r) * N + nb + tx];
  __syncthreads();
  for (int r = ty; r < 32; r += 8)
    wt[(size_t)(nb + r) * K + kb + tx] = (f16)tile[tx][r];
}

// ---- 128x128 tile GEMM, A [M][K] f16, Bt [N][K] f16, BK=32 ----
template<int MODE>
__global__ __launch_bounds__(256, 2)
void gemm128(const f16* __restrict__ A, const f16* __restrict__ Bt,
             const float* __restrict__ bias, float* __restrict__ Cf,
             f16* __restrict__ Qb, f16* __restrict__ Kb, f16* __restrict__ Vt,
             int M, int N, int K, int nbx)
{
  __shared__ f16 Ash[128 * 32];
  __shared__ f16 Bsh[128 * 32];
  const int tid = threadIdx.x;
  const int bid = blockIdx.x;
  const int nb = bid % nbx, mb = bid / nbx;
  const int m0 = mb * 128, n0 = nb * 128;
  const int lane = tid & 63, wid = tid >> 6;
  const int wr = wid >> 1, wc = wid & 1;
  const int l16 = lane & 15, l4 = lane >> 4;

  f32x4 acc[4][4] = {};

  const int f0 = tid, f1 = tid + 256;
  const f16* a0 = A + (size_t)(m0 + (f0 >> 2)) * K + (f0 & 3) * 8;
  const f16* a1 = A + (size_t)(m0 + (f1 >> 2)) * K + (f1 & 3) * 8;
  const f16* b0 = Bt + (size_t)(n0 + (f0 >> 2)) * K + (f0 & 3) * 8;
  const f16* b1 = Bt + (size_t)(n0 + (f1 >> 2)) * K + (f1 & 3) * 8;
  f16* lA0 = Ash + f0 * 8; f16* lA1 = Ash + f1 * 8;
  f16* lB0 = Bsh + f0 * 8; f16* lB1 = Bsh + f1 * 8;

  for (int k0 = 0; k0 < K; k0 += 32) {
    gld_lds16(a0 + k0, lA0);
    gld_lds16(a1 + k0, lA1);
    gld_lds16(b0 + k0, lB0);
    gld_lds16(b1 + k0, lB1);
    __syncthreads();
    f16x8 af[4], bfr[4];
    #pragma unroll
    for (int m = 0; m < 4; ++m)
      af[m] = *(const f16x8*)(Ash + (wr * 64 + m * 16 + l16) * 32 + l4 * 8);
    #pragma unroll
    for (int n = 0; n < 4; ++n)
      bfr[n] = *(const f16x8*)(Bsh + (wc * 64 + n * 16 + l16) * 32 + l4 * 8);
    #pragma unroll
    for (int m = 0; m < 4; ++m)
      #pragma unroll
      for (int n = 0; n < 4; ++n)
        acc[m][n] = __builtin_amdgcn_mfma_f32_16x16x32_f16(af[m], bfr[n], acc[m][n], 0, 0, 0);
    __syncthreads();
  }

  const int cbase = n0 + wc * 64;
  const int rbase = m0 + wr * 64;
  if (MODE == 1) {
    #pragma unroll
    for (int n = 0; n < 4; ++n) {
      int c = cbase + n * 16 + l16;
      float bv = bias[c];
      #pragma unroll
      for (int m = 0; m < 4; ++m)
        #pragma unroll
        for (int r = 0; r < 4; ++r) {
          int rr = rbase + m * 16 + l4 * 4 + r;
          Cf[(size_t)rr * N + c] = acc[m][n][r] + bv;
        }
    }
  } else {
    #pragma unroll
    for (int n = 0; n < 4; ++n) {
      int c = cbase + n * 16 + l16;
      float bv = bias[c];
      int which = c / DQ;
      int rem = c - which * DQ;
      int h = rem >> 6, hd = rem & 63;
      #pragma unroll
      for (int m = 0; m < 4; ++m)
        #pragma unroll
        for (int r = 0; r < 4; ++r) {
          int rr = rbase + m * 16 + l4 * 4 + r;
          int b = rr >> 11, s = rr & 2047;
          float v = acc[m][n][r] + bv;
          size_t bh = (size_t)(b * HQ + h);
          if (which == 0)      Qb[(bh * SQ + s) * HD + hd] = (f16)(v * 0.125f);
          else if (which == 1) Kb[(bh * SQ + s) * HD + hd] = (f16)v;
          else                 Vt[(bh * HD + hd) * SQ + s] = (f16)v;
        }
    }
  }
}

// K-row permutation: LDS row p holds global K row t0+perm(p).
// Maps C-slot (n,l4,r) [t_lds = n*16+l4*4+r] onto B-slot k = (n&1)*32+l4*8+(n>>1)*4+r.
__device__ __forceinline__ int permK(int p) {
  return ((p & 16) << 1) | (((p >> 2) & 3) << 3) | ((p & 32) >> 3) | (p & 3);
}

// ---- flash attention v3 ----
// 1 block = 64 q rows (4 waves x 16). Swapped QK^T: sacc = mfma(K,Q) -> lane
// holds 16 scores of ONE query (s=l16). In-register softmax (2 shfl rounds).
// P feeds PV B-operand directly via permuted-K staging (no LDS P, no bpermute).
// K/V tiles double-buffered, XOR bank swizzle via pre-swizzled global source.
__global__ __launch_bounds__(256, 5)
void attn(const f16* __restrict__ Qb, const f16* __restrict__ Kb,
          const f16* __restrict__ Vt, f16* __restrict__ O)
{
  __shared__ f16 Ksh[2][KVB * HD];   // [t'][d] swizzled rows (permuted), 2x8 KB
  __shared__ f16 Vsh[2][HD * KVB];   // [d][t'] swizzled rows (linear t), 2x8 KB
  const int tid = threadIdx.x, lane = tid & 63, wid = tid >> 6;
  const int l16 = lane & 15, l4 = lane >> 4;

  // bijective XCD swizzle: 1536 blocks (%8==0)
  const int nwg = gridDim.x;
  const int cpx = nwg >> 3;
  const int swz = (blockIdx.x & 7) * cpx + (blockIdx.x >> 3);
  const int qt = swz & 31, bh = swz >> 5;
  const int b = bh / HQ, h = bh - b * HQ;
  const f16* q  = Qb + (size_t)bh * SQ * HD;
  const f16* kp = Kb + (size_t)bh * SQ * HD;
  const f16* vp = Vt + (size_t)bh * HD * SQ;
  const int s0 = qt * 64 + wid * 16;

  // Q fragment (B-operand): col = l16 (query), k = kk*32 + l4*8 + j
  f16x8 qf[2];
  #pragma unroll
  for (int kk = 0; kk < 2; ++kk)
    qf[kk] = *(const f16x8*)(q + (size_t)(s0 + l16) * HD + kk * 32 + l4 * 8);

  f32x4 oacc[4] = {};        // O^T: row d = n*16+l4*4+r, col s = l16
  float mrun = -1e30f, lrun = 0.f;

  // staging geometry: thread covers LDS bytes [tid*16,+16); dest row p = tid>>3.
  const int p0 = tid >> 3, p1 = (tid >> 3) + 32;
  const int scS = ((tid & 7) ^ (p0 & 7)) * 8;            // XOR'd source col (f16 units)
  const int kr0 = permK(p0), kr1 = permK(p1);            // permuted K source rows

#define STAGE(buf, t0)                                                        \
  do {                                                                        \
    gld_lds16(kp + (size_t)((t0) + kr0) * HD + scS, Ksh[buf] + tid * 8);      \
    gld_lds16(kp + (size_t)((t0) + kr1) * HD + scS, Ksh[buf] + (tid + 256) * 8);\
    gld_lds16(vp + (size_t)p0 * SQ + (t0) + scS,   Vsh[buf] + tid * 8);       \
    gld_lds16(vp + (size_t)p1 * SQ + (t0) + scS,   Vsh[buf] + (tid + 256) * 8);\
  } while (0)

#define COMPUTE(buf)                                                          \
  do {                                                                        \
    f32x4 sacc[4] = {};                                                       \
    _Pragma("unroll")                                                         \
    for (int kk = 0; kk < 2; ++kk) {                                          \
      f16x8 kf[4];                                                            \
      _Pragma("unroll")                                                       \
      for (int n = 0; n < 4; ++n)                                             \
        kf[n] = *(const f16x8*)(Ksh[buf] + (n * 16 + l16) * HD +              \
                                ((kk * 32 + l4 * 8) ^ ((l16 & 7) * 8)));      \
      _Pragma("unroll")                                                       \
      for (int n = 0; n < 4; ++n)                                             \
        sacc[n] = __builtin_amdgcn_mfma_f32_16x16x32_f16(kf[n], qf[kk], sacc[n], 0, 0, 0); \
    }                                                                         \
    float rm = -1e30f;                                                        \
    _Pragma("unroll")                                                         \
    for (int n = 0; n < 4; ++n) {                                             \
      float a = fmaxf(fmaxf(sacc[n][0], sacc[n][1]), fmaxf(sacc[n][2], sacc[n][3])); \
      rm = fmaxf(rm, a);                                                      \
    }                                                                         \
    rm = fmaxf(rm, __shfl_xor(rm, 16));                                       \
    rm = fmaxf(rm, __shfl_xor(rm, 32));                                       \
    float mn = fmaxf(mrun, rm);                                               \
    float corr = __expf(mrun - mn);                                           \
    mrun = mn;                                                                \
    float ps = 0.f;                                                           \
    _Pragma("unroll")                                                         \
    for (int n = 0; n < 4; ++n)                                               \
      _Pragma("unroll")                                                       \
      for (int r = 0; r < 4; ++r) {                                           \
        float pv = __expf(sacc[n][r] - mn);                                   \
        sacc[n][r] = pv;                                                      \
        ps += pv;                                                             \
      }                                                                       \
    ps += __shfl_xor(ps, 16);                                                 \
    ps += __shfl_xor(ps, 32);                                                 \
    lrun = lrun * corr + ps;                                                  \
    _Pragma("unroll")                                                         \
    for (int n = 0; n < 4; ++n)                                               \
      oacc[n] *= corr;                                                        \
    f16x8 bfr[2];                                                             \
    _Pragma("unroll")                                                         \
    for (int n = 0; n < 4; ++n)                                               \
      _Pragma("unroll")                                                       \
      for (int r = 0; r < 4; ++r)                                             \
        bfr[n & 1][(n >> 1) * 4 + r] = (f16)sacc[n][r];                       \
    _Pragma("unroll")                                                         \
    for (int kk = 0; kk < 2; ++kk) {                                          \
      f16x8 vf[4];                                                            \
      _Pragma("unroll")                                                       \
      for (int n = 0; n < 4; ++n)                                             \
        vf[n] = *(const f16x8*)(Vsh[buf] + (n * 16 + l16) * KVB +             \
                                ((kk * 32 + l4 * 8) ^ ((l16 & 7) * 8)));      \
      _Pragma("unroll")                                                       \
      for (int n = 0; n < 4; ++n)                                             \
        oacc[n] = __builtin_amdgcn_mfma_f32_16x16x32_f16(vf[n], bfr[kk], oacc[n], 0, 0, 0); \
    }                                                                         \
  } while (0)

  STAGE(0, 0);
  __syncthreads();
  for (int t0 = 0; t0 < SQ; t0 += 2 * KVB) {
    STAGE(1, t0 + KVB);
    COMPUTE(0);
    __syncthreads();
    if (t0 + 2 * KVB < SQ) STAGE(0, t0 + 2 * KVB);
    COMPUTE(1);
    __syncthreads();
  }
#undef STAGE
#undef COMPUTE

  // epilogue: lane owns query s = s0+l16, d = n*16 + l4*4 + r -> 8B stores
  float inv = 1.f / lrun;
  const int s = s0 + l16;
  f16* obase = O + ((size_t)b * SQ + s) * DQ + h * HD + l4 * 4;
  #pragma unroll
  for (int n = 0; n < 4; ++n) {
    f16x4 ov = { (f16)(oacc[n][0] * inv), (f16)(oacc[n][1] * inv),
                 (f16)(oacc[n][2] * inv), (f16)(oacc[n][3] * inv) };
    *(f16x4*)(obase + n * 16) = ov;
  }
}

extern "C" void kernel_launch(void* const* d_in, const int* in_sizes, int n_in,
                              void* d_out, int out_size, void* d_ws, size_t ws_size,
                              hipStream_t stream) {
  const float* x      = (const float*)d_in[0];
  const float* w_qkv  = (const float*)d_in[1];
  const float* b_qkv  = (const float*)d_in[2];
  const float* w_proj = (const float*)d_in[3];
  const float* b_proj = (const float*)d_in[4];
  float* out = (float*)d_out;

  char* ws = (char*)d_ws;
  f16* xh     = (f16*)ws; ws += (size_t)M_TOK * DQ * 2;
  f16* wqkvT  = (f16*)ws; ws += (size_t)3 * DQ * DQ * 2;
  f16* wprojT = (f16*)ws; ws += (size_t)DQ * DQ * 2;
  f16* Qb     = (f16*)ws; ws += (size_t)M_TOK * DQ * 2;
  f16* Kb     = (f16*)ws; ws += (size_t)M_TOK * DQ * 2;
  f16* Vt     = (f16*)ws; ws += (size_t)M_TOK * DQ * 2;
  f16* AO     = xh;  // attn output; xh fully consumed by qkv GEMM before attn

  cvt_x<<<(M_TOK * DQ) / (256 * 4), 256, 0, stream>>>(x, xh, M_TOK * DQ);
  cvt_transpose<<<dim3((3 * DQ) / 32, DQ / 32), 256, 0, stream>>>(w_qkv, wqkvT, DQ, 3 * DQ);
  cvt_transpose<<<dim3(DQ / 32, DQ / 32), 256, 0, stream>>>(w_proj, wprojT, DQ, DQ);

  gemm128<0><<<(M_TOK / 128) * (3 * DQ / 128), 256, 0, stream>>>(
      xh, wqkvT, b_qkv, nullptr, Qb, Kb, Vt, M_TOK, 3 * DQ, DQ, 3 * DQ / 128);

  attn<<<BQ * HQ * (SQ / 64), 256, 0, stream>>>(Qb, Kb, Vt, AO);

  gemm128<1><<<(M_TOK / 128) * (DQ / 128), 256, 0, stream>>>(
      AO, wprojT, b_proj, out, nullptr, nullptr, nullptr, M_TOK, DQ, DQ, DQ / 128);
}

// Round 4
// 168.555 us; speedup vs baseline: 1.6819x; 1.1594x over previous
//
#include <hip/hip_runtime.h>

// MHA forward: B=4, S=2048, D=768, H=12, Hd=64
// cvt(x,w) -> qkv GEMM (fp16 MFMA) -> flash attn (swapped-QK, 2 q-groups/wave,
// exp2 softmax, defer-max, permuted-K staging, dbuf LDS, setprio) -> proj GEMM.

typedef _Float16 f16;
typedef _Float16 f16x8 __attribute__((ext_vector_type(8)));
typedef _Float16 f16x4 __attribute__((ext_vector_type(4)));
typedef float f32x4 __attribute__((ext_vector_type(4)));

#define BQ 4
#define SQ 2048
#define DQ 768
#define HQ 12
#define HD 64
#define M_TOK (BQ*SQ)      // 8192
#define KVB 64
#define QSCALE 0.18033688f  // 0.125 * log2(e): scores land in exp2 domain
#define THR_LOG2 11.5f      // defer-max threshold (~e^8)

__device__ __forceinline__ void gld_lds16(const f16* g, f16* l) {
  __builtin_amdgcn_global_load_lds((const __attribute__((address_space(1))) void*)g,
                                   (__attribute__((address_space(3))) void*)l,
                                   16, 0, 0);
}

// ---- converts ----
__global__ void cvt_x(const float* __restrict__ x, f16* __restrict__ xh, int n) {
  int i = (blockIdx.x * blockDim.x + threadIdx.x) * 4;
  if (i < n) {
    float4 v = *(const float4*)(x + i);
    f16x4 o = { (f16)v.x, (f16)v.y, (f16)v.z, (f16)v.w };
    *(f16x4*)(xh + i) = o;
  }
}

// w [K][N] f32 -> wt [N][K] f16
__global__ void cvt_transpose(const float* __restrict__ w, f16* __restrict__ wt, int K, int N) {
  __shared__ float tile[32][33];
  int nb = blockIdx.x * 32, kb = blockIdx.y * 32;
  int tx = threadIdx.x & 31, ty = threadIdx.x >> 5;
  for (int r = ty; r < 32; r += 8)
    tile[r][tx] = w[(size_t)(kb + r) * N + nb + tx];
  __syncthreads();
  for (int r = ty; r < 32; r += 8)
    wt[(size_t)(nb + r) * K + kb + tx] = (f16)tile[tx][r];
}

// ---- 128x128 tile GEMM, A [M][K] f16, Bt [N][K] f16, BK=32 ----
template<int MODE>
__global__ __launch_bounds__(256, 2)
void gemm128(const f16* __restrict__ A, const f16* __restrict__ Bt,
             const float* __restrict__ bias, float* __restrict__ Cf,
             f16* __restrict__ Qb, f16* __restrict__ Kb, f16* __restrict__ Vt,
             int M, int N, int K, int nbx)
{
  __shared__ f16 Ash[128 * 32];
  __shared__ f16 Bsh[128 * 32];
  const int tid = threadIdx.x;
  const int bid = blockIdx.x;
  const int nb = bid % nbx, mb = bid / nbx;
  const int m0 = mb * 128, n0 = nb * 128;
  const int lane = tid & 63, wid = tid >> 6;
  const int wr = wid >> 1, wc = wid & 1;
  const int l16 = lane & 15, l4 = lane >> 4;

  f32x4 acc[4][4] = {};

  const int f0 = tid, f1 = tid + 256;
  const f16* a0 = A + (size_t)(m0 + (f0 >> 2)) * K + (f0 & 3) * 8;
  const f16* a1 = A + (size_t)(m0 + (f1 >> 2)) * K + (f1 & 3) * 8;
  const f16* b0 = Bt + (size_t)(n0 + (f0 >> 2)) * K + (f0 & 3) * 8;
  const f16* b1 = Bt + (size_t)(n0 + (f1 >> 2)) * K + (f1 & 3) * 8;
  f16* lA0 = Ash + f0 * 8; f16* lA1 = Ash + f1 * 8;
  f16* lB0 = Bsh + f0 * 8; f16* lB1 = Bsh + f1 * 8;

  for (int k0 = 0; k0 < K; k0 += 32) {
    gld_lds16(a0 + k0, lA0);
    gld_lds16(a1 + k0, lA1);
    gld_lds16(b0 + k0, lB0);
    gld_lds16(b1 + k0, lB1);
    __syncthreads();
    f16x8 af[4], bfr[4];
    #pragma unroll
    for (int m = 0; m < 4; ++m)
      af[m] = *(const f16x8*)(Ash + (wr * 64 + m * 16 + l16) * 32 + l4 * 8);
    #pragma unroll
    for (int n = 0; n < 4; ++n)
      bfr[n] = *(const f16x8*)(Bsh + (wc * 64 + n * 16 + l16) * 32 + l4 * 8);
    #pragma unroll
    for (int m = 0; m < 4; ++m)
      #pragma unroll
      for (int n = 0; n < 4; ++n)
        acc[m][n] = __builtin_amdgcn_mfma_f32_16x16x32_f16(af[m], bfr[n], acc[m][n], 0, 0, 0);
    __syncthreads();
  }

  const int cbase = n0 + wc * 64;
  const int rbase = m0 + wr * 64;
  if (MODE == 1) {
    #pragma unroll
    for (int n = 0; n < 4; ++n) {
      int c = cbase + n * 16 + l16;
      float bv = bias[c];
      #pragma unroll
      for (int m = 0; m < 4; ++m)
        #pragma unroll
        for (int r = 0; r < 4; ++r) {
          int rr = rbase + m * 16 + l4 * 4 + r;
          Cf[(size_t)rr * N + c] = acc[m][n][r] + bv;
        }
    }
  } else {
    #pragma unroll
    for (int n = 0; n < 4; ++n) {
      int c = cbase + n * 16 + l16;
      float bv = bias[c];
      int which = c / DQ;
      int rem = c - which * DQ;
      int h = rem >> 6, hd = rem & 63;
      #pragma unroll
      for (int m = 0; m < 4; ++m) {
        int rr0 = rbase + m * 16 + l4 * 4;          // 4 consecutive tokens, same b
        int b = rr0 >> 11, s = rr0 & 2047;
        size_t bh = (size_t)(b * HQ + h);
        if (which == 2) {
          // V^T: consecutive r -> consecutive s -> vectorized 8B store
          f16x4 ov = { (f16)(acc[m][n][0] + bv), (f16)(acc[m][n][1] + bv),
                       (f16)(acc[m][n][2] + bv), (f16)(acc[m][n][3] + bv) };
          *(f16x4*)(Vt + (bh * HD + hd) * SQ + s) = ov;
        } else if (which == 0) {
          #pragma unroll
          for (int r = 0; r < 4; ++r)
            Qb[(bh * SQ + s + r) * HD + hd] = (f16)((acc[m][n][r] + bv) * QSCALE);
        } else {
          #pragma unroll
          for (int r = 0; r < 4; ++r)
            Kb[(bh * SQ + s + r) * HD + hd] = (f16)(acc[m][n][r] + bv);
        }
      }
    }
  }
}

// K-row permutation: LDS row p holds global K row t0+perm(p).
// Maps C-slot (n,l4,r) [t_lds = n*16+l4*4+r] onto B-slot k = (n&1)*32+l4*8+(n>>1)*4+r.
__device__ __forceinline__ int permK(int p) {
  return ((p & 16) << 1) | (((p >> 2) & 3) << 3) | ((p & 32) >> 3) | (p & 3);
}

// ---- flash attention v4 ----
// 1 block = 128 q rows (4 waves x 32: two 16-row groups per wave sharing K/V
// LDS tiles). Swapped QK^T -> lane owns one query per group (s=l16), softmax
// fully in-register (2 shfl rounds), exp2 domain, defer-max, P feeds PV
// B-operand via permuted-K staging. K/V dbuf, XOR bank swizzle.
__global__ __launch_bounds__(256, 3)
void attn(const f16* __restrict__ Qb, const f16* __restrict__ Kb,
          const f16* __restrict__ Vt, f16* __restrict__ O)
{
  __shared__ f16 Ksh[2][KVB * HD];   // [t'][d] swizzled rows (permuted), 2x8 KB
  __shared__ f16 Vsh[2][HD * KVB];   // [d][t'] swizzled rows (linear t), 2x8 KB
  const int tid = threadIdx.x, lane = tid & 63, wid = tid >> 6;
  const int l16 = lane & 15, l4 = lane >> 4;

  // bijective XCD swizzle: 768 blocks (%8==0), 96/XCD
  const int nwg = gridDim.x;
  const int cpx = nwg >> 3;
  const int swz = (blockIdx.x & 7) * cpx + (blockIdx.x >> 3);
  const int qt = swz & 15, bh = swz >> 4;
  const int b = bh / HQ, h = bh - b * HQ;
  const f16* q  = Qb + (size_t)bh * SQ * HD;
  const f16* kp = Kb + (size_t)bh * SQ * HD;
  const f16* vp = Vt + (size_t)bh * HD * SQ;
  const int s0 = qt * 128 + wid * 32;

  // Q fragments (B-operand): [group][kk], col = group query s0+g*16+l16
  f16x8 qf[2][2];
  #pragma unroll
  for (int g = 0; g < 2; ++g)
    #pragma unroll
    for (int kk = 0; kk < 2; ++kk)
      qf[g][kk] = *(const f16x8*)(q + (size_t)(s0 + g * 16 + l16) * HD + kk * 32 + l4 * 8);

  f32x4 oacc[2][4] = {};     // [group]: O^T row d = n*16+l4*4+r, col s = l16
  float mrun[2] = { -1e30f, -1e30f }, lrun[2] = { 0.f, 0.f };

  // staging: thread covers LDS bytes [tid*16,+16); dest row p = tid>>3.
  const int p0 = tid >> 3, p1 = (tid >> 3) + 32;
  const int scS = ((tid & 7) ^ (p0 & 7)) * 8;            // XOR'd source col
  const int kr0 = permK(p0), kr1 = permK(p1);            // permuted K source rows

#define STAGE(buf, t0)                                                        \
  do {                                                                        \
    gld_lds16(kp + (size_t)((t0) + kr0) * HD + scS, Ksh[buf] + tid * 8);      \
    gld_lds16(kp + (size_t)((t0) + kr1) * HD + scS, Ksh[buf] + (tid + 256) * 8);\
    gld_lds16(vp + (size_t)p0 * SQ + (t0) + scS,   Vsh[buf] + tid * 8);       \
    gld_lds16(vp + (size_t)p1 * SQ + (t0) + scS,   Vsh[buf] + (tid + 256) * 8);\
  } while (0)

#define COMPUTE(buf)                                                          \
  do {                                                                        \
    f32x4 sacc[2][4] = {};                                                    \
    __builtin_amdgcn_s_setprio(1);                                            \
    _Pragma("unroll")                                                         \
    for (int kk = 0; kk < 2; ++kk) {                                          \
      f16x8 kf[4];                                                            \
      _Pragma("unroll")                                                       \
      for (int n = 0; n < 4; ++n)                                             \
        kf[n] = *(const f16x8*)(Ksh[buf] + (n * 16 + l16) * HD +              \
                                ((kk * 32 + l4 * 8) ^ ((l16 & 7) * 8)));      \
      _Pragma("unroll")                                                       \
      for (int n = 0; n < 4; ++n) {                                           \
        sacc[0][n] = __builtin_amdgcn_mfma_f32_16x16x32_f16(kf[n], qf[0][kk], sacc[0][n], 0, 0, 0); \
        sacc[1][n] = __builtin_amdgcn_mfma_f32_16x16x32_f16(kf[n], qf[1][kk], sacc[1][n], 0, 0, 0); \
      }                                                                       \
    }                                                                         \
    __builtin_amdgcn_s_setprio(0);                                            \
    f16x8 bfr[2][2];                                                          \
    _Pragma("unroll")                                                         \
    for (int g = 0; g < 2; ++g) {                                             \
      float rm = -1e30f;                                                      \
      _Pragma("unroll")                                                       \
      for (int n = 0; n < 4; ++n)                                             \
        rm = fmaxf(rm, fmaxf(fmaxf(sacc[g][n][0], sacc[g][n][1]),             \
                             fmaxf(sacc[g][n][2], sacc[g][n][3])));           \
      rm = fmaxf(rm, __shfl_xor(rm, 16));                                     \
      rm = fmaxf(rm, __shfl_xor(rm, 32));                                     \
      if (!__all(rm - mrun[g] <= THR_LOG2)) {                                 \
        float mn = fmaxf(mrun[g], rm);                                        \
        float corr = __builtin_amdgcn_exp2f(mrun[g] - mn);                    \
        lrun[g] *= corr;                                                      \
        _Pragma("unroll")                                                     \
        for (int n = 0; n < 4; ++n)                                           \
          oacc[g][n] *= corr;                                                 \
        mrun[g] = mn;                                                         \
      }                                                                       \
      float mref = mrun[g];                                                   \
      float ps = 0.f;                                                         \
      _Pragma("unroll")                                                       \
      for (int n = 0; n < 4; ++n)                                             \
        _Pragma("unroll")                                                     \
        for (int r = 0; r < 4; ++r) {                                         \
          float pv = __builtin_amdgcn_exp2f(sacc[g][n][r] - mref);            \
          bfr[g][n & 1][(n >> 1) * 4 + r] = (f16)pv;                          \
          ps += pv;                                                           \
        }                                                                     \
      ps += __shfl_xor(ps, 16);                                               \
      ps += __shfl_xor(ps, 32);                                               \
      lrun[g] += ps;                                                          \
    }                                                                         \
    __builtin_amdgcn_s_setprio(1);                                            \
    _Pragma("unroll")                                                         \
    for (int kk = 0; kk < 2; ++kk) {                                          \
      f16x8 vf[4];                                                            \
      _Pragma("unroll")                                                       \
      for (int n = 0; n < 4; ++n)                                             \
        vf[n] = *(const f16x8*)(Vsh[buf] + (n * 16 + l16) * KVB +             \
                                ((kk * 32 + l4 * 8) ^ ((l16 & 7) * 8)));      \
      _Pragma("unroll")                                                       \
      for (int n = 0; n < 4; ++n) {                                           \
        oacc[0][n] = __builtin_amdgcn_mfma_f32_16x16x32_f16(vf[n], bfr[0][kk], oacc[0][n], 0, 0, 0); \
        oacc[1][n] = __builtin_amdgcn_mfma_f32_16x16x32_f16(vf[n], bfr[1][kk], oacc[1][n], 0, 0, 0); \
      }                                                                       \
    }                                                                         \
    __builtin_amdgcn_s_setprio(0);                                            \
  } while (0)

  STAGE(0, 0);
  __syncthreads();
  for (int t0 = 0; t0 < SQ; t0 += 2 * KVB) {
    STAGE(1, t0 + KVB);
    COMPUTE(0);
    __syncthreads();
    if (t0 + 2 * KVB < SQ) STAGE(0, t0 + 2 * KVB);
    COMPUTE(1);
    __syncthreads();
  }
#undef STAGE
#undef COMPUTE

  // epilogue: per group, lane owns query s = s0+g*16+l16; 8B stores
  #pragma unroll
  for (int g = 0; g < 2; ++g) {
    float inv = 1.f / lrun[g];
    const int s = s0 + g * 16 + l16;
    f16* obase = O + ((size_t)b * SQ + s) * DQ + h * HD + l4 * 4;
    #pragma unroll
    for (int n = 0; n < 4; ++n) {
      f16x4 ov = { (f16)(oacc[g][n][0] * inv), (f16)(oacc[g][n][1] * inv),
                   (f16)(oacc[g][n][2] * inv), (f16)(oacc[g][n][3] * inv) };
      *(f16x4*)(obase + n * 16) = ov;
    }
  }
}

extern "C" void kernel_launch(void* const* d_in, const int* in_sizes, int n_in,
                              void* d_out, int out_size, void* d_ws, size_t ws_size,
                              hipStream_t stream) {
  const float* x      = (const float*)d_in[0];
  const float* w_qkv  = (const float*)d_in[1];
  const float* b_qkv  = (const float*)d_in[2];
  const float* w_proj = (const float*)d_in[3];
  const float* b_proj = (const float*)d_in[4];
  float* out = (float*)d_out;

  char* ws = (char*)d_ws;
  f16* xh     = (f16*)ws; ws += (size_t)M_TOK * DQ * 2;
  f16* wqkvT  = (f16*)ws; ws += (size_t)3 * DQ * DQ * 2;
  f16* wprojT = (f16*)ws; ws += (size_t)DQ * DQ * 2;
  f16* Qb     = (f16*)ws; ws += (size_t)M_TOK * DQ * 2;
  f16* Kb     = (f16*)ws; ws += (size_t)M_TOK * DQ * 2;
  f16* Vt     = (f16*)ws; ws += (size_t)M_TOK * DQ * 2;
  f16* AO     = xh;  // attn output; xh fully consumed by qkv GEMM before attn

  cvt_x<<<(M_TOK * DQ) / (256 * 4), 256, 0, stream>>>(x, xh, M_TOK * DQ);
  cvt_transpose<<<dim3((3 * DQ) / 32, DQ / 32), 256, 0, stream>>>(w_qkv, wqkvT, DQ, 3 * DQ);
  cvt_transpose<<<dim3(DQ / 32, DQ / 32), 256, 0, stream>>>(w_proj, wprojT, DQ, DQ);

  gemm128<0><<<(M_TOK / 128) * (3 * DQ / 128), 256, 0, stream>>>(
      xh, wqkvT, b_qkv, nullptr, Qb, Kb, Vt, M_TOK, 3 * DQ, DQ, 3 * DQ / 128);

  attn<<<BQ * HQ * (SQ / 128), 256, 0, stream>>>(Qb, Kb, Vt, AO);

  gemm128<1><<<(M_TOK / 128) * (DQ / 128), 256, 0, stream>>>(
      AO, wprojT, b_proj, out, nullptr, nullptr, nullptr, M_TOK, DQ, DQ, DQ / 128);
}